// Round 6
// baseline (121.823 us; speedup 1.0000x reference)
//
#include <hip/hip_runtime.h>
#include <hip/hip_bf16.h>

// Problem constants
#define B_   8
#define CIN  128
#define CKEY 256   // N_HEADS*HEAD_DIM key channels
#define NH   8
#define HOUT 32    // OUT_CH / N_HEADS
#define CPH  288   // softmax length per head
#define HW   4096

// LDS geometry — px-HALF blocks: E2 window = 4 rows x 34 cols (32 out px + halo)
#define ESTR   264                 // ch stride per col in bf16 (132 dw, 16B blocks)
#define NCOL   34                  // E2 cols: key px P0-1 .. P0+32
#define EROW2  (NCOL * ESTR)       // 8976 elems per y-row
#define E2_BYTES (4 * EROW2 * 2)   // 71808 B -> 2 blocks/CU (143.6 KB/CU)
#define XCOL_DW 68                 // xbuf dw per col (64 + 4 pad)
#define XROW_DW (48 * XCOL_DW)     // 3264 dw per row slot (48 cols: 34 data + 14 zero)
// xbuf = 4 slots x 13056 B = 52224 B, ALIASED over E2 rows 0..2 (53856 B):
// all conv reads of xbuf complete before barrier 2; E2 writes after it.
#define SMEM_BYTES E2_BYTES

typedef __attribute__((ext_vector_type(8))) short bf16x8;
typedef __attribute__((ext_vector_type(4))) float f32x4;

static __device__ __forceinline__ unsigned bfpack2(float a, float b) {  // RNE pair
  __hip_bfloat162 h = __float22bfloat162_rn(float2{a, b});
  unsigned r;
  __builtin_memcpy(&r, &h, 4);
  return r;
}
static __device__ __forceinline__ unsigned short f2bf(float f) {
  unsigned u = __builtin_bit_cast(unsigned, f);
  u += 0x7FFFu + ((u >> 16) & 1u);
  return (unsigned short)(u >> 16);
}

// ---------------------------------------------------------------------------
// prep_kernel: 36 blocks x 256 thr. Pack memory B-frags (reindexed by m,p,s):
// c = ((m-p)&7)+8s, t = (9c+p)>>3; n-idx li -> i = ib*16+li, k = q*8+j -> s.
// (Register-resident gather in fused spills at the 128-VGPR cap — r1, r5.)
// ---------------------------------------------------------------------------
__global__ __launch_bounds__(256) void prep_kernel(
    const float* __restrict__ mem, unsigned short* __restrict__ mfragP)
{
  const int idx  = blockIdx.x * 256 + threadIdx.x;  // 0..9215
  const int lane = idx & 63, fi = idx >> 6;         // fi 0..143
  const int ib = fi & 1, pm = fi >> 1;
  const int p = pm % 9, m = pm / 9;
  const int li = lane & 15, q = lane >> 4;
  const int i = ib * 16 + li;
  unsigned short* dst = mfragP + (size_t)idx * 8;
#pragma unroll
  for (int j = 0; j < 8; ++j) {
    const int s = q * 8 + j;
    const int c = ((m - p + 8) & 7) + 8 * s;
    const int t = (9 * c + p) >> 3;
    dst[j] = f2bf(mem[((size_t)m * CPH + t) * HOUT + i]);
  }
}

// ---------------------------------------------------------------------------
// Fused conv + softmax + matvec, h-PAIR x px-HALF per block, 512 threads.
// grid = 512 (b = bid&7 XCD swizzle, t = bid>>3: ph = t&1, h0 = 2*(t>>1)).
// LDS 71.8 KB -> TWO independent blocks/CU: latency of one block's
// load/store/barrier drains hides under the other block's compute (the 1-block
// h-pair variants r0/r3/r4 were all pinned at the same time regardless of
// intra-block schedule — the missing ingredient is an independent co-tenant).
// __launch_bounds__(512,4): 4 waves/EU = 2 blocks/CU, VGPR cap 128; conv acc
// is sized to fit (acc[4][2][3] = 96 VGPR) — no spill (tripwire: WRITE_SIZE).
// Phases:
//  0) x loads for 4 rows x 33 real cols (halo col + cols 34..47 zeroed);
//     wf gather; stage into per-row xbuf slots
//  B1) conv MFMA all rows, 3 px-tiles (48 cols computed, 34 kept)
//  B2) exp + E2 writes (xbuf dead; E2 rows 0..2 alias it); border col +
//      out-of-range rows = 1.0 = exp(0)
//  B3) attention per hh: wave = head m; per (p,pb): one ds_read_b128 A-frag
//      from E2; SWAPPED-operand MFMA: mfma(mem, attn) -> D[i][px];
//      denominator mfma(ones, attn); scale + direct coalesced stores
// ---------------------------------------------------------------------------
__global__ __launch_bounds__(512, 4) void fused_kernel(
    const float* __restrict__ x, const float* __restrict__ wk,
    const unsigned short* __restrict__ mfragP, const float* __restrict__ bk,
    float* __restrict__ out)
{
  extern __shared__ char smem[];
  unsigned short* e2 = (unsigned short*)smem;
  unsigned*       xdw = (unsigned*)smem;    // 4 row slots, dead after barrier 2

  const int tid = threadIdx.x;
  const int bid = blockIdx.x;
  const int b  = bid & 7;                   // XCD swizzle: batch per XCD
  const int t  = bid >> 3;
  const int ph = t & 1;                     // px half: out px P0..P0+31
  const int h0 = (t >> 1) * 2;
  const int P0 = ph * 32;
  const int lane = tid & 63;
  const int wv = __builtin_amdgcn_readfirstlane(tid >> 6);  // 0..7
  const int li = lane & 15, q = lane >> 4;

  // ---- bias, permuted: tile (cm=wv, sh), row r -> och = wv + 8*(sh*16+4q+r)
  float bias[2][4];
#pragma unroll
  for (int sh = 0; sh < 2; ++sh)
#pragma unroll
    for (int r = 0; r < 4; ++r)
      bias[sh][r] = bk[wv + 8 * (sh * 16 + 4 * q + r)];

  const bool valid[4] = {h0 - 1 >= 0, true, true, h0 + 2 < 64};
  // E2 col ec <-> global key px P0-1+ec; conv-valid cols:
  const int cmin = ph ? 0 : 1;
  const int cmax = ph ? 32 : 33;

  // ================= phase 0: x loads (33 real cols x 128 ic) =============
  // pair-slots: icp-major (coalesced 136B runs): slot = icp*34 + c
  unsigned pk[4][5];
#pragma unroll
  for (int rr = 0; rr < 4; ++rr) {
    if (!valid[rr]) continue;
    const int y = h0 - 1 + rr;
    const float* xb = x + (size_t)b * CIN * HW + (size_t)y * 64;
#pragma unroll
    for (int it = 0; it < 5; ++it) {
      const int slot = it * 512 + tid;
      unsigned v = 0u;
      if (slot < 64 * NCOL) {
        const int icp = slot / NCOL;          // ic pair 0..63
        const int c   = slot - icp * NCOL;    // local col 0..33
        if (c >= cmin && c <= cmax) {
          const int gpx = P0 - 1 + c;         // 0..63
          const float v0 = xb[(size_t)(2 * icp) * HW + gpx];
          const float v1 = xb[(size_t)(2 * icp + 1) * HW + gpx];
          v = bfpack2(v0, v1);
        }
      }
      pk[rr][it] = v;
    }
  }

  // ---- in-kernel W A-frags (och = wv + 8*(sh*16+li), ic = ks*32+q*8+j)
  bf16x8 wf[2][4];
#pragma unroll
  for (int sh = 0; sh < 2; ++sh)
#pragma unroll
    for (int ks = 0; ks < 4; ++ks) {
      const int och = wv + 8 * (sh * 16 + li);
      const float* src = wk + (size_t)och * CIN + ks * 32 + q * 8;
      const float4 v0 = *(const float4*)(src);
      const float4 v1 = *(const float4*)(src + 4);
      const int4 piv = make_int4(bfpack2(v0.x, v0.y), bfpack2(v0.z, v0.w),
                                 bfpack2(v1.x, v1.y), bfpack2(v1.z, v1.w));
      wf[sh][ks] = __builtin_bit_cast(bf16x8, piv);
    }

  // ---- zero xbuf cols 34..47 (pt=2 overshoot) in all 4 row slots
  for (int d = tid; d < 4 * 14 * XCOL_DW; d += 512) {
    const int rr  = d / (14 * XCOL_DW);
    const int rem = d - rr * (14 * XCOL_DW);
    const int ci  = rem / XCOL_DW;
    const int o   = rem - ci * XCOL_DW;
    xdw[rr * XROW_DW + (NCOL + ci) * XCOL_DW + o] = 0u;
  }

  // ---- stage rows into xbuf slots (dw icp at col c, 8-dw-block XOR swizzle;
  //      invalid halo col stages 0 = its zero-fill)
#pragma unroll
  for (int rr = 0; rr < 4; ++rr) {
    if (!valid[rr]) continue;
#pragma unroll
    for (int it = 0; it < 5; ++it) {
      const int slot = it * 512 + tid;
      if (slot < 64 * NCOL) {
        const int icp = slot / NCOL;
        const int c   = slot - icp * NCOL;
        xdw[rr * XROW_DW + c * XCOL_DW + (icp ^ (((c >> 3) & 7) << 3))] =
            pk[rr][it];
      }
    }
  }
  __syncthreads();                          // ===== barrier 1 =====

  // ================= phase 1: conv, all rows, 3 px-tiles =================
  f32x4 acc[4][2][3];                       // [rr][sh][pt] = 96 VGPR
#pragma unroll
  for (int rr = 0; rr < 4; ++rr)
#pragma unroll
    for (int sh = 0; sh < 2; ++sh)
#pragma unroll
      for (int pt = 0; pt < 3; ++pt) {
        f32x4 cv; cv[0] = bias[sh][0]; cv[1] = bias[sh][1];
        cv[2] = bias[sh][2]; cv[3] = bias[sh][3];
        acc[rr][sh][pt] = cv;
      }
#pragma unroll
  for (int ks = 0; ks < 4; ++ks) {
    const bf16x8 a0 = wf[0][ks];
    const bf16x8 a1 = wf[1][ks];
#pragma unroll
    for (int rr = 0; rr < 4; ++rr) {
      if (!valid[rr]) continue;
#pragma unroll
      for (int pt = 0; pt < 3; ++pt) {
        const int c   = pt * 16 + li;
        const int blk = (ks * 16 + q * 4) ^ (((c >> 3) & 7) << 3);
        const bf16x8 bfr = *(const bf16x8*)(xdw + rr * XROW_DW + c * XCOL_DW + blk);
        acc[rr][0][pt] = __builtin_amdgcn_mfma_f32_16x16x32_bf16(a0, bfr, acc[rr][0][pt], 0, 0, 0);
        acc[rr][1][pt] = __builtin_amdgcn_mfma_f32_16x16x32_bf16(a1, bfr, acc[rr][1][pt], 0, 0, 0);
      }
    }
  }
  __syncthreads();                          // ===== barrier 2 (xbuf dead) ====

  // ================= phase 2: exp + E2 writes =================
#pragma unroll
  for (int rr = 0; rr < 4; ++rr) {
    if (!valid[rr]) continue;
    unsigned short* erow = e2 + rr * EROW2;
#pragma unroll
    for (int sh = 0; sh < 2; ++sh)
#pragma unroll
      for (int pt = 0; pt < 3; ++pt) {
        const int ec = pt * 16 + li;
        if (ec >= cmin && ec <= cmax) {     // conv-valid cols only
          const float w0 = __expf(acc[rr][sh][pt][0]);
          const float w1 = __expf(acc[rr][sh][pt][1]);
          const float w2 = __expf(acc[rr][sh][pt][2]);
          const float w3 = __expf(acc[rr][sh][pt][3]);
          unsigned short* dst = erow + ec * ESTR + wv * 32 + sh * 16 + 4 * q;
          *(uint2*)dst = make_uint2(bfpack2(w0, w1), bfpack2(w2, w3));
        }
      }
    if (tid < 128) {                        // halo border col = exp(0) = 1.0
      const int ec = ph ? 33 : 0;
      ((unsigned*)(erow + ec * ESTR))[tid] = 0x3F803F80u;
    }
  }
  // out-of-range rows -> 1.0 everywhere (rows 0/3; alias-safe post-B2)
#pragma unroll
  for (int r = 0; r < 4; r += 3) {
    if (!valid[r]) {
      unsigned* erow = (unsigned*)(e2 + r * EROW2);
      for (int d = tid; d < NCOL * (ESTR / 2); d += 512) erow[d] = 0x3F803F80u;
    }
  }
  __syncthreads();                          // ===== barrier 3 =====

  // ================= phase 3+4: attention per h =================
  const int m = wv;                         // wave = head
  const unsigned short* mf = mfragP + (size_t)(m * 9) * 2 * 64 * 8;
  const int4 onesi = make_int4(0x3F803F80, 0x3F803F80, 0x3F803F80, 0x3F803F80);
  const bf16x8 bones = __builtin_bit_cast(bf16x8, onesi);

#pragma unroll
  for (int hh = 0; hh < 2; ++hh) {
    f32x4 acc2[2][2], accs[2];
#pragma unroll
    for (int pb = 0; pb < 2; ++pb) {
      acc2[pb][0] = {0.f, 0.f, 0.f, 0.f};
      acc2[pb][1] = {0.f, 0.f, 0.f, 0.f};
      accs[pb]    = {0.f, 0.f, 0.f, 0.f};
    }
#pragma unroll
    for (int p = 0; p < 9; ++p) {
      const bf16x8 bm0 = *(const bf16x8*)(mf + ((size_t)((p * 2 + 0) * 64 + lane)) * 8);
      const bf16x8 bm1 = *(const bf16x8*)(mf + ((size_t)((p * 2 + 1) * 64 + lane)) * 8);
      const int cmp  = (m - p + 8) & 7;
      const int rrow = hh + p / 3;
      const int dxp  = p - 3 * (p / 3);
      const unsigned short* abase = e2 + rrow * EROW2 + (li + dxp) * ESTR
                                  + cmp * 32 + q * 8;
#pragma unroll
      for (int pb = 0; pb < 2; ++pb) {
        const bf16x8 af = *(const bf16x8*)(abase + pb * 16 * ESTR);  // b128
        // swapped operands: A = memory (row=i), B = attn (col=px)
        acc2[pb][0] = __builtin_amdgcn_mfma_f32_16x16x32_bf16(bm0, af, acc2[pb][0], 0, 0, 0);
        acc2[pb][1] = __builtin_amdgcn_mfma_f32_16x16x32_bf16(bm1, af, acc2[pb][1], 0, 0, 0);
        accs[pb]    = __builtin_amdgcn_mfma_f32_16x16x32_bf16(bones, af, accs[pb], 0, 0, 0);
      }
    }
    float* ob = out + ((size_t)(b * CKEY + m * HOUT)) * HW + (h0 + hh) * 64 + P0;
#pragma unroll
    for (int pb = 0; pb < 2; ++pb) {
      // A = ones makes every accs row the per-pixel denominator (px = li)
      const float inv = 1.0f / accs[pb][0];
#pragma unroll
      for (int n = 0; n < 2; ++n)
#pragma unroll
        for (int r = 0; r < 4; ++r)
          ob[(size_t)(n * 16 + 4 * q + r) * HW + pb * 16 + li] =
              acc2[pb][n][r] * inv;         // 64B segments per store instr
    }
  }
}

extern "C" void kernel_launch(void* const* d_in, const int* in_sizes, int n_in,
                              void* d_out, int out_size, void* d_ws, size_t ws_size,
                              hipStream_t stream) {
  const float* x   = (const float*)d_in[0];
  const float* wk  = (const float*)d_in[1];
  const float* bk  = (const float*)d_in[2];
  const float* mem = (const float*)d_in[3];

  unsigned short* mfragP = (unsigned short*)d_ws;   // 147,456 B

  (void)hipFuncSetAttribute((const void*)fused_kernel,
                            hipFuncAttributeMaxDynamicSharedMemorySize, SMEM_BYTES);

  prep_kernel<<<dim3(36), dim3(256), 0, stream>>>(mem, mfragP);
  fused_kernel<<<dim3(512), dim3(512), SMEM_BYTES, stream>>>(
      x, wk, mfragP, bk, (float*)d_out);
}

// Round 8
// 113.497 us; speedup vs baseline: 1.0734x; 1.0734x over previous
//
#include <hip/hip_runtime.h>
#include <hip/hip_bf16.h>

// Problem constants
#define B_   8
#define CIN  128
#define CKEY 256   // N_HEADS*HEAD_DIM key channels
#define NH   8
#define HOUT 32    // OUT_CH / N_HEADS
#define CPH  288   // softmax length per head
#define HW   4096

// LDS geometry — SINGLE-h px-HALF blocks: E2 = 3 rows x 34 cols, no aliasing
#define ESTR   264                 // ch stride per col in bf16 (132 dw, 16B blocks)
#define NCOL   34                  // E2 cols: key px P0-1 .. P0+32
#define EROW2  (NCOL * ESTR)       // 8976 elems per y-row
#define E2_BYTES (3 * EROW2 * 2)   // 53856 B
#define XCOL_DW 68                 // xbuf dw per col (64 data + 4 pad)
#define XNCOL  48                  // 34 data cols + 14 zero cols (pt=2 overshoot)
#define XBUF_BYTES (XNCOL * XCOL_DW * 4)     // 13056 B
#define SMEM_BYTES (E2_BYTES + XBUF_BYTES)   // 66912 B -> 2 blocks/CU (133.8 KB)

typedef __attribute__((ext_vector_type(8))) short bf16x8;
typedef __attribute__((ext_vector_type(4))) float f32x4;

static __device__ __forceinline__ unsigned bfpack2(float a, float b) {  // RNE pair
  __hip_bfloat162 h = __float22bfloat162_rn(float2{a, b});
  unsigned r;
  __builtin_memcpy(&r, &h, 4);
  return r;
}
static __device__ __forceinline__ unsigned short f2bf(float f) {
  unsigned u = __builtin_bit_cast(unsigned, f);
  u += 0x7FFFu + ((u >> 16) & 1u);
  return (unsigned short)(u >> 16);
}

// ---------------------------------------------------------------------------
// prep_kernel: 36 blocks x 256 thr. Pack memory B-frags (reindexed by m,p,s):
// c = ((m-p)&7)+8s, t = (9c+p)>>3; n-idx li -> i = ib*16+li, k = q*8+j -> s.
// (Register-resident gather in fused spills at the VGPR cap — r1, r5, r6.)
// ---------------------------------------------------------------------------
__global__ __launch_bounds__(256) void prep_kernel(
    const float* __restrict__ mem, unsigned short* __restrict__ mfragP)
{
  const int idx  = blockIdx.x * 256 + threadIdx.x;  // 0..9215
  const int lane = idx & 63, fi = idx >> 6;         // fi 0..143
  const int ib = fi & 1, pm = fi >> 1;
  const int p = pm % 9, m = pm / 9;
  const int li = lane & 15, q = lane >> 4;
  const int i = ib * 16 + li;
  unsigned short* dst = mfragP + (size_t)idx * 8;
#pragma unroll
  for (int j = 0; j < 8; ++j) {
    const int s = q * 8 + j;
    const int c = ((m - p + 8) & 7) + 8 * s;
    const int t = (9 * c + p) >> 3;
    dst[j] = f2bf(mem[((size_t)m * CPH + t) * HOUT + i]);
  }
}

// ---------------------------------------------------------------------------
// Fused conv + softmax + matvec, SINGLE-h x px-HALF per block, 512 threads.
// grid = 1024 (b = bid&7 XCD swizzle, t = bid>>3: ph = t&1, h = t>>1).
// LDS 66.9 KB -> TWO blocks/CU. Register footprint sized for the 128-total
// cap at 4 waves/EU (r6 lesson: cap INCLUDES AGPR accumulators; acc there
// was 96 and spilled into a 64/64 split). Here: conv acc[2][3]=24 +
// attn acc 12 AGPR; arch ~55 -> fits. Tripwire: WRITE_SIZE >> 34 MB = spill.
// Per block: conv rows y = h-1..h+1 (computed redundantly vs neighbors --
// conv is 8% MfmaUtil, redundancy is free); barrier chain is private to the
// block, and the co-resident block hides every drain (the r0/r3/r4 1-block
// variants were pinned at ~33 us regardless of schedule; OccupancyPercent
// 40.7 in r6 proved 2-blocks/CU engages).
// Phases per row rr (0..2): stage xbuf -> B -> conv MFMA + exp + E2 row -> B.
// Then attention: per (p,pb): ds_read_b128 A-frag; SWAPPED-operand MFMA
// mfma(mem, attn) -> D[i][px]; denominator mfma(ones, attn); direct stores.
// ---------------------------------------------------------------------------
__global__ __launch_bounds__(512, 4) void fused_kernel(
    const float* __restrict__ x, const float* __restrict__ wk,
    const unsigned short* __restrict__ mfragP, const float* __restrict__ bk,
    float* __restrict__ out)
{
  extern __shared__ char smem[];
  unsigned short* e2 = (unsigned short*)smem;
  unsigned*       xdw = (unsigned*)(smem + E2_BYTES);   // single xbuf slot

  const int tid = threadIdx.x;
  const int bid = blockIdx.x;
  const int b  = bid & 7;                   // XCD swizzle: batch per XCD
  const int t  = bid >> 3;
  const int ph = t & 1;                     // px half: out px P0..P0+31
  const int h  = t >> 1;                    // 0..63
  const int P0 = ph * 32;
  const int lane = tid & 63;
  const int wv = __builtin_amdgcn_readfirstlane(tid >> 6);  // 0..7
  const int li = lane & 15, q = lane >> 4;

  // ---- bias, permuted: tile (cm=wv, sh), row r -> och = wv + 8*(sh*16+4q+r)
  float bias[2][4];
#pragma unroll
  for (int sh = 0; sh < 2; ++sh)
#pragma unroll
    for (int r = 0; r < 4; ++r)
      bias[sh][r] = bk[wv + 8 * (sh * 16 + 4 * q + r)];

  // conv-valid E2 cols (ec <-> global key px P0-1+ec); halo col is border
  const int cmin = ph ? 0 : 1;
  const int cmax = ph ? 32 : 33;

  // ---- in-kernel W A-frags (och = wv + 8*(sh*16+li), ic = ks*32+q*8+j)
  bf16x8 wf[2][4];
#pragma unroll
  for (int sh = 0; sh < 2; ++sh)
#pragma unroll
    for (int ks = 0; ks < 4; ++ks) {
      const int och = wv + 8 * (sh * 16 + li);
      const float* src = wk + (size_t)och * CIN + ks * 32 + q * 8;
      const float4 v0 = *(const float4*)(src);
      const float4 v1 = *(const float4*)(src + 4);
      const int4 piv = make_int4(bfpack2(v0.x, v0.y), bfpack2(v0.z, v0.w),
                                 bfpack2(v1.x, v1.y), bfpack2(v1.z, v1.w));
      wf[sh][ks] = __builtin_bit_cast(bf16x8, piv);
    }

  // ---- phase 0 (pre-barrier): zero xbuf pad cols 34..47; 1.0-fill invalid
  //      E2 rows (top/bottom ZeroPad rows -> exp(0) = 1.0)
  for (int d = tid; d < 14 * XCOL_DW; d += 512) {
    const int ci = d / XCOL_DW, o = d - ci * XCOL_DW;
    xdw[(NCOL + ci) * XCOL_DW + o] = 0u;
  }
#pragma unroll
  for (int rr = 0; rr < 3; rr += 2) {       // rr=0 (y=h-1), rr=2 (y=h+1)
    const int y = h - 1 + rr;
    if (y < 0 || y > 63) {
      unsigned* erow = (unsigned*)(e2 + rr * EROW2);
      for (int d = tid; d < NCOL * (ESTR / 2); d += 512) erow[d] = 0x3F803F80u;
    }
  }

  // ================= conv rows (per-row: stage -> B -> conv+exp+E2 -> B) ===
  for (int rr = 0; rr < 3; ++rr) {
    const int y = h - 1 + rr;
    const bool vrow = (y >= 0) && (y <= 63);
    if (vrow) {                             // stage 34 cols x 64 ic-pairs
      const float* xb = x + (size_t)b * CIN * HW + (size_t)y * 64;
#pragma unroll
      for (int it = 0; it < 5; ++it) {
        const int slot = it * 512 + tid;
        if (slot < 64 * NCOL) {
          const int icp = slot / NCOL;      // ic pair 0..63
          const int c   = slot - icp * NCOL;// local col 0..33
          unsigned v = 0u;
          if (c >= cmin && c <= cmax) {     // guard: gpx in 0..63
            const int gpx = P0 - 1 + c;
            const float v0 = xb[(size_t)(2 * icp) * HW + gpx];
            const float v1 = xb[(size_t)(2 * icp + 1) * HW + gpx];
            v = bfpack2(v0, v1);
          }
          xdw[c * XCOL_DW + (icp ^ (((c >> 3) & 7) << 3))] = v;
        }
      }
    }
    __syncthreads();                        // xbuf ready (uniform branch)
    if (vrow) {
      f32x4 acc[2][3];                      // [sh][pt] = 24 regs
#pragma unroll
      for (int sh = 0; sh < 2; ++sh)
#pragma unroll
        for (int pt = 0; pt < 3; ++pt) {
          f32x4 cv; cv[0] = bias[sh][0]; cv[1] = bias[sh][1];
          cv[2] = bias[sh][2]; cv[3] = bias[sh][3];
          acc[sh][pt] = cv;
        }
#pragma unroll
      for (int ks = 0; ks < 4; ++ks) {
        const bf16x8 a0 = wf[0][ks];
        const bf16x8 a1 = wf[1][ks];
#pragma unroll
        for (int pt = 0; pt < 3; ++pt) {
          const int c   = pt * 16 + li;
          const int blk = (ks * 16 + q * 4) ^ (((c >> 3) & 7) << 3);
          const bf16x8 bfr = *(const bf16x8*)(xdw + c * XCOL_DW + blk);
          acc[0][pt] = __builtin_amdgcn_mfma_f32_16x16x32_bf16(a0, bfr, acc[0][pt], 0, 0, 0);
          acc[1][pt] = __builtin_amdgcn_mfma_f32_16x16x32_bf16(a1, bfr, acc[1][pt], 0, 0, 0);
        }
      }
      // exp + E2 row write (E2 disjoint from xbuf -> no intra-phase hazard)
      unsigned short* erow = e2 + rr * EROW2;
#pragma unroll
      for (int sh = 0; sh < 2; ++sh)
#pragma unroll
        for (int pt = 0; pt < 3; ++pt) {
          const int ec = pt * 16 + li;
          if (ec >= cmin && ec <= cmax) {
            const float w0 = __expf(acc[sh][pt][0]);
            const float w1 = __expf(acc[sh][pt][1]);
            const float w2 = __expf(acc[sh][pt][2]);
            const float w3 = __expf(acc[sh][pt][3]);
            unsigned short* dst = erow + ec * ESTR + wv * 32 + sh * 16 + 4 * q;
            *(uint2*)dst = make_uint2(bfpack2(w0, w1), bfpack2(w2, w3));
          }
        }
      if (tid < 128) {                      // halo border col = exp(0) = 1.0
        const int ec = ph ? 33 : 0;
        ((unsigned*)(erow + ec * ESTR))[tid] = 0x3F803F80u;
      }
    }
    __syncthreads();                        // conv reads done; E2 row visible
  }

  // ================= attention (single h) =================
  const int m = wv;                         // wave = head
  const unsigned short* mf = mfragP + (size_t)(m * 9) * 2 * 64 * 8;
  const int4 onesi = make_int4(0x3F803F80, 0x3F803F80, 0x3F803F80, 0x3F803F80);
  const bf16x8 bones = __builtin_bit_cast(bf16x8, onesi);

  f32x4 acc2[2][2], accs[2];
#pragma unroll
  for (int pb = 0; pb < 2; ++pb) {
    acc2[pb][0] = {0.f, 0.f, 0.f, 0.f};
    acc2[pb][1] = {0.f, 0.f, 0.f, 0.f};
    accs[pb]    = {0.f, 0.f, 0.f, 0.f};
  }
#pragma unroll
  for (int p = 0; p < 9; ++p) {
    const bf16x8 bm0 = *(const bf16x8*)(mf + ((size_t)((p * 2 + 0) * 64 + lane)) * 8);
    const bf16x8 bm1 = *(const bf16x8*)(mf + ((size_t)((p * 2 + 1) * 64 + lane)) * 8);
    const int cmp  = (m - p + 8) & 7;
    const int rloc = p / 3;                 // E2 local row
    const int dxp  = p - 3 * rloc;
    const unsigned short* abase = e2 + rloc * EROW2 + (li + dxp) * ESTR
                                + cmp * 32 + q * 8;
#pragma unroll
    for (int pb = 0; pb < 2; ++pb) {
      const bf16x8 af = *(const bf16x8*)(abase + pb * 16 * ESTR);  // b128
      // swapped operands: A = memory (row=i), B = attn (col=px)
      acc2[pb][0] = __builtin_amdgcn_mfma_f32_16x16x32_bf16(bm0, af, acc2[pb][0], 0, 0, 0);
      acc2[pb][1] = __builtin_amdgcn_mfma_f32_16x16x32_bf16(bm1, af, acc2[pb][1], 0, 0, 0);
      accs[pb]    = __builtin_amdgcn_mfma_f32_16x16x32_bf16(bones, af, accs[pb], 0, 0, 0);
    }
  }
  float* ob = out + ((size_t)(b * CKEY + m * HOUT)) * HW + h * 64 + P0;
#pragma unroll
  for (int pb = 0; pb < 2; ++pb) {
    // A = ones makes every accs row the per-pixel denominator (px = li)
    const float inv = 1.0f / accs[pb][0];
#pragma unroll
    for (int n = 0; n < 2; ++n)
#pragma unroll
      for (int r = 0; r < 4; ++r)
        ob[(size_t)(n * 16 + 4 * q + r) * HW + pb * 16 + li] =
            acc2[pb][n][r] * inv;           // 64B segments per store instr
  }
}

extern "C" void kernel_launch(void* const* d_in, const int* in_sizes, int n_in,
                              void* d_out, int out_size, void* d_ws, size_t ws_size,
                              hipStream_t stream) {
  const float* x   = (const float*)d_in[0];
  const float* wk  = (const float*)d_in[1];
  const float* bk  = (const float*)d_in[2];
  const float* mem = (const float*)d_in[3];

  unsigned short* mfragP = (unsigned short*)d_ws;   // 147,456 B

  (void)hipFuncSetAttribute((const void*)fused_kernel,
                            hipFuncAttributeMaxDynamicSharedMemorySize, SMEM_BYTES);

  prep_kernel<<<dim3(36), dim3(256), 0, stream>>>(mem, mfragP);
  fused_kernel<<<dim3(1024), dim3(512), SMEM_BYTES, stream>>>(
      x, wk, mfragP, bk, (float*)d_out);
}

// Round 9
// 95.585 us; speedup vs baseline: 1.2745x; 1.1874x over previous
//
#include <hip/hip_runtime.h>
#include <hip/hip_bf16.h>

// Problem constants
#define B_   8
#define CIN  128
#define CKEY 256   // N_HEADS*HEAD_DIM key channels
#define NH   8
#define HOUT 32    // OUT_CH / N_HEADS
#define CPH  288   // softmax length per head
#define HW   4096

// LDS geometry
#define ESTR   264                 // E2 x-stride in bf16 (132 dw; 16B-aligned blocks)
#define EROW   (66 * ESTR)         // 17424 elems per y-row
#define E2_BYTES   (4 * EROW * 2)  // 139392 (rows h0-1..h0+2)
#define XROW_DW    (64 * 68)       // 4352 dw per x-row slot
// xdw4 = 4 slots x 17408 B = 69632 B, ALIASED over E2 rows 0-1 (69696 B):
// all conv reads of xdw4 complete before barrier 2; E2 writes after it.
#define SMEM_BYTES E2_BYTES        // 139392 <= 160 KiB

typedef __attribute__((ext_vector_type(8))) short bf16x8;
typedef __attribute__((ext_vector_type(4))) float f32x4;

static __device__ __forceinline__ unsigned bfpack2(float a, float b) {  // RNE pair
  __hip_bfloat162 h = __float22bfloat162_rn(float2{a, b});
  unsigned r;
  __builtin_memcpy(&r, &h, 4);
  return r;
}

// ---------------------------------------------------------------------------
// SINGLE-DISPATCH fused conv + softmax + matvec, h-PAIR per block, 512 thr.
// grid = 256 (b = bid&7 XCD swizzle, hp = bid>>3, h0 = 2*hp) = 1 block/CU.
// Structure = r4 (best healthy monolith, ~33 us) + prep_kernel ELIMINATED:
// the memory B-frags are gathered inline in the attention loop, p-OUTER, so
// their live range is ~24 regs inside one p-iteration (r1/r5/r6 spilled
// because mfr[9][2]=72 regs was held ACROSS the conv phase; here nothing is
// held). Attention acc (96) + gather (24) < conv phase's proven ~178 live.
// Schedule levers (waves/SIMD r3, barrier count r4, blocks/CU r8) are all
// measured nulls/losses — this targets the remaining dispatch + gap.
// Phases:
//  0) issue ALL x global loads + wf gather; write all 4 x-row LDS slots
//  B1) conv MFMA for ALL rows back-to-back (acc[4][2][4] in regs)
//  B2) exp + E2 writes for all rows (xdw4 dead; E2 rows 0-1 alias it)
//  B3) attention, p-outer: gather mem tap-p frags from L2 -> 24 MFMA
//      (2 hh x 4 pb x {2 out + 1 ones-denominator}); SWAPPED operands:
//      mfma(mem, attn) -> D[i][px]; epilogue scales + direct coalesced stores
// ---------------------------------------------------------------------------
__global__ __launch_bounds__(512) void fused_kernel(
    const float* __restrict__ x, const float* __restrict__ wk,
    const float* __restrict__ mem, const float* __restrict__ bk,
    float* __restrict__ out)
{
  extern __shared__ char smem[];
  unsigned short* e2 = (unsigned short*)smem;
  unsigned*       xdw = (unsigned*)smem;    // 4 row slots, dead after barrier 2

  const int tid = threadIdx.x;
  const int bid = blockIdx.x;
  const int b  = bid & 7;                   // XCD swizzle: batch per XCD
  const int h0 = (bid >> 3) * 2;
  const int lane = tid & 63;
  const int wv = __builtin_amdgcn_readfirstlane(tid >> 6);  // 0..7
  const int li = lane & 15, q = lane >> 4;

  // ---- bias, permuted: tile (cm=wv, sh), row r -> och = wv + 8*(sh*16+4q+r)
  float bias[2][4];
#pragma unroll
  for (int sh = 0; sh < 2; ++sh)
#pragma unroll
    for (int r = 0; r < 4; ++r)
      bias[sh][r] = bk[wv + 8 * (sh * 16 + 4 * q + r)];

  // ================= phase 0: all x loads up-front =================
  const int spx = tid & 63, sicg = tid >> 6;
  const int sxor = ((spx >> 3) & 7) << 3;   // 16B-block bank swizzle

  const bool valid[4] = {h0 - 1 >= 0, true, true, h0 + 2 < 64};
  unsigned pk[4][8];
#pragma unroll
  for (int r = 0; r < 4; ++r) {
    if (!valid[r]) continue;
    const int y = h0 - 1 + r;
    const float* xr = x + (size_t)b * CIN * HW + y * 64 + spx;
#pragma unroll
    for (int r4 = 0; r4 < 4; ++r4) {
      const int ic0 = 4 * sicg + 32 * r4;
      const float v0 = xr[(size_t)(ic0 + 0) * HW];   // 256B coalesced each
      const float v1 = xr[(size_t)(ic0 + 1) * HW];
      const float v2 = xr[(size_t)(ic0 + 2) * HW];
      const float v3 = xr[(size_t)(ic0 + 3) * HW];
      pk[r][2 * r4 + 0] = bfpack2(v0, v1);
      pk[r][2 * r4 + 1] = bfpack2(v2, v3);
    }
  }

  // ---- in-kernel W A-frags (och = wv + 8*(sh*16+li), ic = ks*32+q*8+j)
  bf16x8 wf[2][4];
#pragma unroll
  for (int sh = 0; sh < 2; ++sh)
#pragma unroll
    for (int ks = 0; ks < 4; ++ks) {
      const int och = wv + 8 * (sh * 16 + li);
      const float* src = wk + (size_t)och * CIN + ks * 32 + q * 8;
      const float4 v0 = *(const float4*)(src);
      const float4 v1 = *(const float4*)(src + 4);
      const int4 piv = make_int4(bfpack2(v0.x, v0.y), bfpack2(v0.z, v0.w),
                                 bfpack2(v1.x, v1.y), bfpack2(v1.z, v1.w));
      wf[sh][ks] = __builtin_bit_cast(bf16x8, piv);
    }

  // ---- stage ALL valid rows into their own LDS slots
#pragma unroll
  for (int rr = 0; rr < 4; ++rr) {
    if (!valid[rr]) continue;
#pragma unroll
    for (int r4 = 0; r4 < 4; ++r4) {
      const int o = (2 * sicg + 16 * r4) ^ sxor;
      *(uint2*)(xdw + rr * XROW_DW + spx * 68 + o) =
          make_uint2(pk[rr][2 * r4], pk[rr][2 * r4 + 1]);
    }
  }
  __syncthreads();                          // ===== barrier 1 =====

  // ================= phase 1: conv, ALL rows, no barriers =================
  f32x4 acc[4][2][4];                       // [rr][sh][pt] = 128 regs
#pragma unroll
  for (int rr = 0; rr < 4; ++rr)
#pragma unroll
    for (int sh = 0; sh < 2; ++sh)
#pragma unroll
      for (int pt = 0; pt < 4; ++pt) {
        f32x4 cv; cv[0] = bias[sh][0]; cv[1] = bias[sh][1];
        cv[2] = bias[sh][2]; cv[3] = bias[sh][3];
        acc[rr][sh][pt] = cv;
      }
#pragma unroll
  for (int ks = 0; ks < 4; ++ks) {
    const bf16x8 a0 = wf[0][ks];
    const bf16x8 a1 = wf[1][ks];
#pragma unroll
    for (int rr = 0; rr < 4; ++rr) {
      if (!valid[rr]) continue;
#pragma unroll
      for (int pt = 0; pt < 4; ++pt) {
        const int px  = pt * 16 + li;
        const int blk = (ks * 16 + q * 4) ^ (((px >> 3) & 7) << 3);
        const bf16x8 bfr = *(const bf16x8*)(xdw + rr * XROW_DW + px * 68 + blk);
        acc[rr][0][pt] = __builtin_amdgcn_mfma_f32_16x16x32_bf16(a0, bfr, acc[rr][0][pt], 0, 0, 0);
        acc[rr][1][pt] = __builtin_amdgcn_mfma_f32_16x16x32_bf16(a1, bfr, acc[rr][1][pt], 0, 0, 0);
      }
    }
  }
  __syncthreads();                          // ===== barrier 2 (xdw4 dead) ====

  // ================= phase 2: exp + E2 writes, all rows =================
#pragma unroll
  for (int rr = 0; rr < 4; ++rr) {
    if (!valid[rr]) continue;
    unsigned short* erow = e2 + rr * EROW;
#pragma unroll
    for (int sh = 0; sh < 2; ++sh)
#pragma unroll
      for (int pt = 0; pt < 4; ++pt) {
        const float w0 = __expf(acc[rr][sh][pt][0]);
        const float w1 = __expf(acc[rr][sh][pt][1]);
        const float w2 = __expf(acc[rr][sh][pt][2]);
        const float w3 = __expf(acc[rr][sh][pt][3]);
        unsigned short* dst = erow + (pt * 16 + li + 1) * ESTR
                            + wv * 32 + sh * 16 + 4 * q;
        *(uint2*)dst = make_uint2(bfpack2(w0, w1), bfpack2(w2, w3));
      }
    if (tid < 256) {                        // x-borders = exp(0) = 1.0
      const int xcol = (tid & 1) ? 65 : 0;
      ((unsigned*)(erow + xcol * ESTR))[tid >> 1] = 0x3F803F80u;
    }
  }
  // out-of-range rows -> exp(0) = 1.0 everywhere (rows 0/3 alias-safe now)
#pragma unroll
  for (int r = 0; r < 4; r += 3) {
    if (!valid[r]) {
      unsigned* erow = (unsigned*)(e2 + r * EROW);
      for (int d = tid; d < 66 * 132; d += 512) erow[d] = 0x3F803F80u;
    }
  }
  __syncthreads();                          // ===== barrier 3 =====

  // ========== phase 3: attention, p-OUTER with inline mem gather ==========
  const int m = wv;                         // wave = head
  const int4 onesi = make_int4(0x3F803F80, 0x3F803F80, 0x3F803F80, 0x3F803F80);
  const bf16x8 bones = __builtin_bit_cast(bf16x8, onesi);

  f32x4 acc2[2][4][2], accs[2][4];          // [hh][pb][n] = 96 regs
#pragma unroll
  for (int hh = 0; hh < 2; ++hh)
#pragma unroll
    for (int pb = 0; pb < 4; ++pb) {
      acc2[hh][pb][0] = {0.f, 0.f, 0.f, 0.f};
      acc2[hh][pb][1] = {0.f, 0.f, 0.f, 0.f};
      accs[hh][pb]    = {0.f, 0.f, 0.f, 0.f};
    }

#pragma unroll
  for (int p = 0; p < 9; ++p) {
    // ---- inline tap-p B-frag gather (replaces prep_kernel):
    // elem j: s = q*8+j; c = ((m-p)&7)+8s; t = (9c+p)>>3;
    // bm[ib] lane (li,q) = bf16(mem[(m*CPH+t)*HOUT + ib*16+li])
    const int cb = (m - p + 8) & 7;
    bf16x8 bm[2];
#pragma unroll
    for (int ib = 0; ib < 2; ++ib) {
      const int i = ib * 16 + li;
      unsigned pr[4];
#pragma unroll
      for (int jj = 0; jj < 4; ++jj) {
        const int s0 = q * 8 + 2 * jj;
        const int c0 = cb + 8 * s0;
        const int c1 = cb + 8 * (s0 + 1);
        const int t0 = (9 * c0 + p) >> 3;
        const int t1 = (9 * c1 + p) >> 3;
        pr[jj] = bfpack2(mem[((size_t)m * CPH + t0) * HOUT + i],
                         mem[((size_t)m * CPH + t1) * HOUT + i]);
      }
      bm[ib] = __builtin_bit_cast(bf16x8, make_int4(pr[0], pr[1], pr[2], pr[3]));
    }
    const int rbase = p / 3;
    const int dxp   = p - 3 * rbase;
#pragma unroll
    for (int hh = 0; hh < 2; ++hh) {
      const unsigned short* abase = e2 + (hh + rbase) * EROW + (li + dxp) * ESTR
                                  + cb * 32 + q * 8;
#pragma unroll
      for (int pb = 0; pb < 4; ++pb) {
        const bf16x8 af = *(const bf16x8*)(abase + pb * 16 * ESTR);  // b128
        // swapped operands: A = memory (row=i), B = attn (col=px)
        acc2[hh][pb][0] = __builtin_amdgcn_mfma_f32_16x16x32_bf16(bm[0], af, acc2[hh][pb][0], 0, 0, 0);
        acc2[hh][pb][1] = __builtin_amdgcn_mfma_f32_16x16x32_bf16(bm[1], af, acc2[hh][pb][1], 0, 0, 0);
        accs[hh][pb]    = __builtin_amdgcn_mfma_f32_16x16x32_bf16(bones, af, accs[hh][pb], 0, 0, 0);
      }
    }
  }

  // ================= phase 4: epilogue =================
#pragma unroll
  for (int hh = 0; hh < 2; ++hh) {
    float* ob = out + ((size_t)(b * CKEY + m * HOUT)) * HW + (h0 + hh) * 64;
#pragma unroll
    for (int pb = 0; pb < 4; ++pb) {
      // A = ones makes every accs row the per-pixel denominator (px = li)
      const float inv = 1.0f / accs[hh][pb][0];
#pragma unroll
      for (int n = 0; n < 2; ++n)
#pragma unroll
        for (int r = 0; r < 4; ++r)
          ob[(size_t)(n * 16 + 4 * q + r) * HW + pb * 16 + li] =
              acc2[hh][pb][n][r] * inv;     // 4x64B segments per store instr
    }
  }
}

extern "C" void kernel_launch(void* const* d_in, const int* in_sizes, int n_in,
                              void* d_out, int out_size, void* d_ws, size_t ws_size,
                              hipStream_t stream) {
  const float* x   = (const float*)d_in[0];
  const float* wk  = (const float*)d_in[1];
  const float* bk  = (const float*)d_in[2];
  const float* mem = (const float*)d_in[3];
  (void)d_ws; (void)ws_size;

  (void)hipFuncSetAttribute((const void*)fused_kernel,
                            hipFuncAttributeMaxDynamicSharedMemorySize, SMEM_BYTES);

  fused_kernel<<<dim3(256), dim3(512), SMEM_BYTES, stream>>>(
      x, wk, mem, bk, (float*)d_out);
}